// Round 15
// baseline (104.877 us; speedup 1.0000x reference)
//
#include <hip/hip_runtime.h>
#include <math.h>

constexpr int NB = 8, NC = 64, NO = 64, NH = 64, NW = 64;

using f32x4 = __attribute__((ext_vector_type(4))) float;
using s16x8 = __attribute__((ext_vector_type(8))) short;
using u32x4 = __attribute__((ext_vector_type(4))) unsigned int;

// packed f32x2 -> bf16x2 (RNE), v_cvt_pk_bf16_f32 (no builtin on gfx950)
__device__ __forceinline__ unsigned int pk2(float lo, float hi) {
    unsigned int r;
    asm("v_cvt_pk_bf16_f32 %0, %1, %2" : "=v"(r) : "v"(lo), "v"(hi));
    return r;
}
__device__ __forceinline__ unsigned short f2bf(float f) {
    unsigned u = __builtin_bit_cast(unsigned, f);
    return (unsigned short)((u + 0x7fffu + ((u >> 16) & 1u)) >> 16);
}
__device__ __forceinline__ float bf2f(unsigned short s) {
    unsigned u = ((unsigned)s) << 16;
    return __builtin_bit_cast(float, u);
}

// Grid 256 = b(8) x hpair(32) -> exactly 1 block/CU, NO osub split: x fetched ONCE for the
// GEMM (8 MB total vs 32 MB at osub=4) -- attacks the measured 65 MB FETCH over-read.
// Block tile: 2 h-rows x 64 w x ALL 64 o. 512 thr = 8 waves = ofrag(wv&3) x hrow(wv>>2);
// wave = 4 n-tiles of 16 w for its 16-o fragment.
// W streamed per-k through a 2x32KB LDS double-buffer (w_gen is L2-resident; re-reads are
// L2 traffic, not HBM). T14: loadWk(k+1) issued before compute of k, writeWk after.
// MFMA A = W (rows=o), B = x (cols=w). D: row(o)=q*4+reg, col(w)=c0 -> coalesced stores.
// LDS 124 KB; launch_bounds(512,1) -> 256-VGPR budget, live ~140 -> no spill (R5/R7/R11 class).
__global__ __launch_bounds__(512, 1)
void acda_kernel(const float* __restrict__ x, const float* __restrict__ w_gen,
                 const float* __restrict__ b_gen, const float* __restrict__ pos_enc,
                 float* __restrict__ out)
{
    __shared__ unsigned short Xs[128 * 64];        // 16 KB [loc][c] bf16, XOR-swizzled
    __shared__ unsigned short Wk[2][256 * 64];     // 64 KB dbuf: per-k [row=a*64+o][c] bf16 swz
    __shared__ unsigned short Patch[4 * 66 * 68];  // 35.1 KB [hhi][wwi][o(64)+pad4] bf16
    __shared__ float BiasL[9 * 4 * 64];            // 9 KB [k][a][o]

    const int tid  = threadIdx.x;
    const int lane = tid & 63;
    const int wv   = tid >> 6;           // 0..7
    const int c0   = lane & 15, q = lane >> 4;
    const int ofrag = wv & 3, hrow = wv >> 2;

    const int bx    = blockIdx.x;
    const int hbase = (bx & 31) * 2;
    const int b     = bx >> 5;
    const size_t xB = (size_t)b * NC * NH * NW;

    // ---- W staging (T14 split): loadWk -> wl regs (L2 hits), writeWk -> LDS ----
    // unit v = i*512 + tid (i=0..3): row = v>>3 = i*64 + (tid>>3), cseg = tid&7.
    // row = a*64 + o  ->  f = (o*4 + a)*9 + k, 16B bf16 <- 32B f32.
    const int srow0 = tid >> 3, scseg = tid & 7;
    const int sbyte0 = srow0 * 128 + ((scseg * 16) ^ ((srow0 & 7) << 4));
    float4 wl[8];
    auto loadWk = [&](int k) {
#pragma unroll
        for (int i = 0; i < 4; ++i) {
            const int row = i * 64 + srow0;
            const int o = row & 63, a = row >> 6;
            const float* src = w_gen + (size_t)((o * 4 + a) * 9 + k) * NC + scseg * 8;
            wl[2 * i]     = *reinterpret_cast<const float4*>(src);
            wl[2 * i + 1] = *reinterpret_cast<const float4*>(src + 4);
        }
    };
    auto writeWk = [&](int nbuf) {
        unsigned char* base = reinterpret_cast<unsigned char*>(&Wk[nbuf][0]);
#pragma unroll
        for (int i = 0; i < 4; ++i) {
            u32x4 pk;
            pk[0] = pk2(wl[2 * i].x, wl[2 * i].y); pk[1] = pk2(wl[2 * i].z, wl[2 * i].w);
            pk[2] = pk2(wl[2 * i + 1].x, wl[2 * i + 1].y); pk[3] = pk2(wl[2 * i + 1].z, wl[2 * i + 1].w);
            *reinterpret_cast<u32x4*>(base + sbyte0 + i * 8192) = pk;
        }
    };

    loadWk(0);   // k=0 in flight; Xs/Patch/bias staging hides the latency

    // ---- stage Xs: x[b,c,hbase+hs,w] -> Xs[loc = hs*64+w][c] bf16 swz ----
    {
        const int w = lane;
#pragma unroll
        for (int i = 0; i < 2; ++i) {
            const int pair = wv * 2 + i;          // 16 (hs, oct) pairs
            const int hs = pair >> 3, oct = pair & 7;
            const float* src = x + xB + (size_t)(oct * 8) * (NH * NW) + (hbase + hs) * NW + w;
            u32x4 pkv;
#pragma unroll
            for (int j = 0; j < 4; ++j)
                pkv[j] = pk2(src[(size_t)(2 * j) * (NH * NW)], src[(size_t)(2 * j + 1) * (NH * NW)]);
            const int loc  = hs * 64 + w;
            const int byte = loc * 128 + ((oct * 16) ^ ((loc & 7) << 4));
            *reinterpret_cast<u32x4*>(reinterpret_cast<char*>(Xs) + byte) = pkv;
        }
    }
    // ---- stage Patch: x[b,o,hbase-1+hhi,ww] -> Patch[hhi][ww+1][o] bf16 ----
    {
        const int o_l = tid >> 3, w8 = (tid & 7) * 8;
        const float* xo = x + xB + (size_t)o_l * (NH * NW);
#pragma unroll
        for (int hhi = 0; hhi < 4; ++hhi) {
            const int hh = hbase - 1 + hhi;
            float4 v0 = {0.f, 0.f, 0.f, 0.f}, v1 = {0.f, 0.f, 0.f, 0.f};
            if (hh >= 0 && hh < NH) {
                v0 = *reinterpret_cast<const float4*>(xo + hh * NW + w8);
                v1 = *reinterpret_cast<const float4*>(xo + hh * NW + w8 + 4);
            }
            unsigned short* p = Patch + (hhi * 66 + w8 + 1) * 68 + o_l;
            p[0 * 68] = f2bf(v0.x); p[1 * 68] = f2bf(v0.y);
            p[2 * 68] = f2bf(v0.z); p[3 * 68] = f2bf(v0.w);
            p[4 * 68] = f2bf(v1.x); p[5 * 68] = f2bf(v1.y);
            p[6 * 68] = f2bf(v1.z); p[7 * 68] = f2bf(v1.w);
        }
        // zero halo columns wwi = 0, 65 (4 hhi x 2 sides x 64 o = 512 entries)
        const int hhi = tid >> 7, side = (tid >> 6) & 1, ol2 = tid & 63;
        Patch[(hhi * 66 + (side ? 65 : 0)) * 68 + ol2] = 0;
    }
    // ---- stage bias: BiasL[(k*4+a)*64 + o] = b_gen[(o*4+a)*9 + k] ----
    for (int i = tid; i < 2304; i += 512) {
        const int k = i >> 8, a = (i >> 6) & 3, o = i & 63;
        BiasL[i] = b_gen[(o * 4 + a) * 9 + k];
    }
    writeWk(0);
    __syncthreads();   // Xs, Wk[0], Patch, BiasL ready

    // ---- x fragments: 4 n-tiles (one h-row per wave) ----
    s16x8 xf[4][2];
#pragma unroll
    for (int nt = 0; nt < 4; ++nt) {
        const int loc = hrow * 64 + nt * 16 + c0;
#pragma unroll
        for (int kh2 = 0; kh2 < 2; ++kh2) {
            const int byte = loc * 128 + ((kh2 * 64 + q * 16) ^ ((loc & 7) << 4));
            xf[nt][kh2] = *reinterpret_cast<s16x8*>(reinterpret_cast<char*>(Xs) + byte);
        }
    }

    // ---- attention attv[a][nt] ----
    float pe[8];
#pragma unroll
    for (int i = 0; i < 8; ++i) pe[i] = pos_enc[i];
    const float gy = -1.0f + (2.0f / 63.0f) * (float)(hbase + hrow);
    float attv[4][4];
#pragma unroll
    for (int a = 0; a < 4; ++a) {
#pragma unroll
        for (int nt = 0; nt < 4; ++nt) {
            const float gx = -1.0f + (2.0f / 63.0f) * (float)(nt * 16 + c0);
            const float dx = gx - pe[2 * a], dy = gy - pe[2 * a + 1];
            attv[a][nt] = __expf(-(dx * dx + dy * dy));
        }
    }

    const int o4 = ofrag * 16 + q * 4;           // lane's o base
    const int wfr = ofrag * 16 + c0;             // W-frag row (o part); full row = a*64 + wfr
    const int wswz = (wfr & 7) << 4;             // (a*64) & 7 == 0 -> swz independent of a

    float outacc[4][4] = {};

#pragma unroll
    for (int k = 0; k < 9; ++k) {
        const int buf = k & 1;
        if (k < 8) loadWk(k + 1);                // issue-early (T14), L2 hits
        float tsum[4][4] = {};
#pragma unroll
        for (int a = 0; a < 4; ++a) {
            const char* Wt = reinterpret_cast<const char*>(&Wk[buf][0]) + (a * 64 + wfr) * 128;
            const s16x8 wf0 = *reinterpret_cast<const s16x8*>(Wt + ((q * 16) ^ wswz));
            const s16x8 wf1 = *reinterpret_cast<const s16x8*>(Wt + ((64 + q * 16) ^ wswz));
            const f32x4 bb  = *reinterpret_cast<const f32x4*>(BiasL + (k * 4 + a) * 64 + o4);
#pragma unroll
            for (int nt = 0; nt < 4; ++nt) {
                f32x4 acc = bb;
                acc = __builtin_amdgcn_mfma_f32_16x16x32_bf16(wf0, xf[nt][0], acc, 0, 0, 0);
                acc = __builtin_amdgcn_mfma_f32_16x16x32_bf16(wf1, xf[nt][1], acc, 0, 0, 0);
                const float at = attv[a][nt];
#pragma unroll
                for (int r = 0; r < 4; ++r)
                    tsum[nt][r] = fmaf(at, fmaxf(acc[r], 0.f), tsum[nt][r]);
            }
        }
        const int kh = k / 3, kw = k - 3 * kh;
#pragma unroll
        for (int nt = 0; nt < 4; ++nt) {
            const ushort4 pu = *reinterpret_cast<const ushort4*>(
                reinterpret_cast<const char*>(Patch) +
                (((hrow + kh) * 66 + nt * 16 + c0 + kw) * 68 + o4) * 2);
            outacc[nt][0] = fmaf(tsum[nt][0], bf2f(pu.x), outacc[nt][0]);
            outacc[nt][1] = fmaf(tsum[nt][1], bf2f(pu.y), outacc[nt][1]);
            outacc[nt][2] = fmaf(tsum[nt][2], bf2f(pu.z), outacc[nt][2]);
            outacc[nt][3] = fmaf(tsum[nt][3], bf2f(pu.w), outacc[nt][3]);
        }
        if (k < 8) writeWk(buf ^ 1);             // write-late (T14)
        __syncthreads();
    }

    // ---- coalesced stores: 16 consecutive w per 16-lane group ----
    const int h = hbase + hrow;
#pragma unroll
    for (int nt = 0; nt < 4; ++nt) {
        const int wcol = nt * 16 + c0;
#pragma unroll
        for (int r = 0; r < 4; ++r) {
            const int o = o4 + r;
            out[(((size_t)b * NO + o) * NH + h) * NW + wcol] = outacc[nt][r];
        }
    }
}

extern "C" void kernel_launch(void* const* d_in, const int* in_sizes, int n_in,
                              void* d_out, int out_size, void* d_ws, size_t ws_size,
                              hipStream_t stream) {
    const float* x       = (const float*)d_in[0];
    const float* w_gen   = (const float*)d_in[1];
    const float* b_gen   = (const float*)d_in[2];
    const float* pos_enc = (const float*)d_in[3];
    float* out = (float*)d_out;

    dim3 grid(NB * 32);   // 256 workgroups = 1 per CU
    dim3 block(512);
    hipLaunchKernelGGL(acda_kernel, grid, block, 0, stream,
                       x, w_gen, b_gen, pos_enc, out);
}

// Round 16
// 29.429 us; speedup vs baseline: 3.5638x; 3.5638x over previous
//
#include <hip/hip_runtime.h>
#include <math.h>

constexpr int NB = 8, NC = 64, NO = 64, NH = 64, NW = 64;

using f32x4 = __attribute__((ext_vector_type(4))) float;
using s16x8 = __attribute__((ext_vector_type(8))) short;
using u32x4 = __attribute__((ext_vector_type(4))) unsigned int;

// packed f32x2 -> bf16x2 (RNE), v_cvt_pk_bf16_f32 (no builtin on gfx950)
__device__ __forceinline__ unsigned int pk2(float lo, float hi) {
    unsigned int r;
    asm("v_cvt_pk_bf16_f32 %0, %1, %2" : "=v"(r) : "v"(lo), "v"(hi));
    return r;
}
__device__ __forceinline__ float bf2f(unsigned short s) {
    unsigned u = ((unsigned)s) << 16;
    return __builtin_bit_cast(float, u);
}

// Grid 512 = b(8) x h(64) -> 2 blocks/CU (LDS 66.5 KB), 4 waves/SIMD.
// Block tile: 1 h-row x 64 w x ALL 64 o (no osub split -> x fetched once+halo; patch read
// DIRECTLY from Xs: patch channels == x channels, same [loc][c] layout; no Patch array).
// 512 thr = 8 waves = ofrag(wv&3) x whalf(wv>>2); 2 n-tiles of 16 w per wave.
// W streamed per-k through ONE 32 KB LDS buffer; staging in two 16-reg half-batches inside
// a '#pragma unroll 1' loop => max 16 staging VGPRs live, no cross-iteration hoisting
// (R5/R7/R11/R15 spill class: loop-resident staging regs + full unroll).
// MFMA A = W (rows=o), B = x (cols=w). D: row(o)=q*4+reg, col(w)=c0 -> coalesced stores.
__global__ __launch_bounds__(512, 2)
void acda_kernel(const float* __restrict__ x, const float* __restrict__ w_gen,
                 const float* __restrict__ b_gen, const float* __restrict__ pos_enc,
                 float* __restrict__ out)
{
    __shared__ unsigned short Xs[192 * 64];   // 24 KB [loc = hs*64+w][c] bf16 swz, hs: h-1,h,h+1
    __shared__ unsigned short Wk[256 * 64];   // 32 KB per-k [row = a*64+o][c] bf16 swz
    __shared__ float BiasL[9 * 4 * 64];       // 9 KB [(k*4+a)][o]

    const int tid  = threadIdx.x;
    const int lane = tid & 63;
    const int wv   = tid >> 6;            // 0..7
    const int c0   = lane & 15, q = lane >> 4;
    const int ofrag = wv & 3, whalf = wv >> 2;

    const int bx = blockIdx.x;
    const int b  = bx >> 6;
    const int h  = bx & 63;
    const size_t xB = (size_t)b * NC * NH * NW;

    // ---- stage Xs: rows h-1, h, h+1 (zeros outside), x[b,c,hh,w] -> Xs[hs*64+w][c] swz ----
    {
        const int w = lane;
#pragma unroll
        for (int i = 0; i < 3; ++i) {
            const int p = wv * 3 + i;     // 24 (hs, oct) pairs
            const int hs = p >> 3, oct = p & 7;
            const int hh = h - 1 + hs;
            u32x4 pkv = {0, 0, 0, 0};
            if (hh >= 0 && hh < NH) {
                const float* src = x + xB + (size_t)(oct * 8) * (NH * NW) + hh * NW + w;
#pragma unroll
                for (int j = 0; j < 4; ++j)
                    pkv[j] = pk2(src[(size_t)(2 * j) * (NH * NW)], src[(size_t)(2 * j + 1) * (NH * NW)]);
            }
            const int loc  = hs * 64 + w;
            const int byte = loc * 128 + ((oct * 16) ^ ((loc & 7) << 4));
            *reinterpret_cast<u32x4*>(reinterpret_cast<char*>(Xs) + byte) = pkv;
        }
    }
    // ---- stage bias: BiasL[(k*4+a)*64 + o] = b_gen[(o*4+a)*9 + k] ----
    for (int i = tid; i < 2304; i += 512) {
        const int k = i >> 8, a = (i >> 6) & 3, o = i & 63;
        BiasL[i] = b_gen[(o * 4 + a) * 9 + k];
    }
    __syncthreads();   // Xs, BiasL ready

    // ---- x fragments from middle row (hs = 1): 2 n-tiles ----
    s16x8 xf[2][2];
#pragma unroll
    for (int nt = 0; nt < 2; ++nt) {
        const int loc = 64 + whalf * 32 + nt * 16 + c0;
#pragma unroll
        for (int kh2 = 0; kh2 < 2; ++kh2) {
            const int byte = loc * 128 + ((kh2 * 64 + q * 16) ^ ((loc & 7) << 4));
            xf[nt][kh2] = *reinterpret_cast<s16x8*>(reinterpret_cast<char*>(Xs) + byte);
        }
    }

    // ---- attention attv[a][nt] ----
    const float gy = -1.0f + (2.0f / 63.0f) * (float)h;
    float attv[4][2];
#pragma unroll
    for (int a = 0; a < 4; ++a) {
        const float px = pos_enc[2 * a], py = pos_enc[2 * a + 1];
#pragma unroll
        for (int nt = 0; nt < 2; ++nt) {
            const float gx = -1.0f + (2.0f / 63.0f) * (float)(whalf * 32 + nt * 16 + c0);
            const float dx = gx - px, dy = gy - py;
            attv[a][nt] = __expf(-(dx * dx + dy * dy));
        }
    }

    const int o4 = ofrag * 16 + q * 4;        // lane's o base (D rows)
    const int wfr = ofrag * 16 + c0;          // W-frag o-row; full Wk row = a*64 + wfr
    const int wswz = (wfr & 7) << 4;
    const int pchunk = (ofrag * 2 + (q >> 1)) * 16;   // Xs chunk for c = o4 (8B read)
    const int psub = (q & 1) * 8;

    float outacc[2][4] = {};

#pragma unroll 1
    for (int k = 0; k < 9; ++k) {
        __syncthreads();   // previous iteration's Wk reads complete
        // ---- stage Wk for this k: 2048 16B-units, 4/thread in two 16-reg halves ----
#pragma unroll
        for (int half = 0; half < 2; ++half) {
            float4 wa0, wa1, wb0, wb1;
            {
                const int u = (half * 2) * 512 + tid;
                const int row = u >> 3, cseg = u & 7;
                const float* src = w_gen + (size_t)(((row & 63) * 4 + (row >> 6)) * 9 + k) * NC + cseg * 8;
                wa0 = *reinterpret_cast<const float4*>(src);
                wa1 = *reinterpret_cast<const float4*>(src + 4);
            }
            {
                const int u = (half * 2 + 1) * 512 + tid;
                const int row = u >> 3, cseg = u & 7;
                const float* src = w_gen + (size_t)(((row & 63) * 4 + (row >> 6)) * 9 + k) * NC + cseg * 8;
                wb0 = *reinterpret_cast<const float4*>(src);
                wb1 = *reinterpret_cast<const float4*>(src + 4);
            }
            {
                const int u = (half * 2) * 512 + tid;
                const int row = u >> 3, cseg = u & 7;
                u32x4 pk;
                pk[0] = pk2(wa0.x, wa0.y); pk[1] = pk2(wa0.z, wa0.w);
                pk[2] = pk2(wa1.x, wa1.y); pk[3] = pk2(wa1.z, wa1.w);
                const int byte = row * 128 + ((cseg * 16) ^ ((row & 7) << 4));
                *reinterpret_cast<u32x4*>(reinterpret_cast<char*>(Wk) + byte) = pk;
            }
            {
                const int u = (half * 2 + 1) * 512 + tid;
                const int row = u >> 3, cseg = u & 7;
                u32x4 pk;
                pk[0] = pk2(wb0.x, wb0.y); pk[1] = pk2(wb0.z, wb0.w);
                pk[2] = pk2(wb1.x, wb1.y); pk[3] = pk2(wb1.z, wb1.w);
                const int byte = row * 128 + ((cseg * 16) ^ ((row & 7) << 4));
                *reinterpret_cast<u32x4*>(reinterpret_cast<char*>(Wk) + byte) = pk;
            }
        }
        __syncthreads();   // Wk ready

        // ---- compute tap k: all 4 atoms ----
        float tsum[2][4] = {};
#pragma unroll
        for (int a = 0; a < 4; ++a) {
            const char* Wt = reinterpret_cast<const char*>(Wk) + (a * 64 + wfr) * 128;
            const s16x8 wf0 = *reinterpret_cast<const s16x8*>(Wt + ((q * 16) ^ wswz));
            const s16x8 wf1 = *reinterpret_cast<const s16x8*>(Wt + ((64 + q * 16) ^ wswz));
            const f32x4 bb  = *reinterpret_cast<const f32x4*>(BiasL + (k * 4 + a) * 64 + o4);
#pragma unroll
            for (int nt = 0; nt < 2; ++nt) {
                f32x4 acc = bb;
                acc = __builtin_amdgcn_mfma_f32_16x16x32_bf16(wf0, xf[nt][0], acc, 0, 0, 0);
                acc = __builtin_amdgcn_mfma_f32_16x16x32_bf16(wf1, xf[nt][1], acc, 0, 0, 0);
                const float at = attv[a][nt];
#pragma unroll
                for (int r = 0; r < 4; ++r)
                    tsum[nt][r] = fmaf(at, fmaxf(acc[r], 0.f), tsum[nt][r]);
            }
        }
        // ---- patch from Xs + accumulate ----
        const int kh = k / 3, kw = k - 3 * kh;
#pragma unroll
        for (int nt = 0; nt < 2; ++nt) {
            const int ww = whalf * 32 + nt * 16 + c0 + kw - 1;
            const bool wok = (ww >= 0) && (ww < NW);
            const int lp = kh * 64 + (wok ? ww : 0);
            const int byte = lp * 128 + (pchunk ^ ((lp & 7) << 4)) + psub;
            const ushort4 pu = *reinterpret_cast<const ushort4*>(
                reinterpret_cast<const char*>(Xs) + byte);
            const float p0 = wok ? bf2f(pu.x) : 0.f;
            const float p1 = wok ? bf2f(pu.y) : 0.f;
            const float p2 = wok ? bf2f(pu.z) : 0.f;
            const float p3 = wok ? bf2f(pu.w) : 0.f;
            outacc[nt][0] = fmaf(tsum[nt][0], p0, outacc[nt][0]);
            outacc[nt][1] = fmaf(tsum[nt][1], p1, outacc[nt][1]);
            outacc[nt][2] = fmaf(tsum[nt][2], p2, outacc[nt][2]);
            outacc[nt][3] = fmaf(tsum[nt][3], p3, outacc[nt][3]);
        }
    }

    // ---- coalesced stores: 16 consecutive w per 16-lane group ----
#pragma unroll
    for (int nt = 0; nt < 2; ++nt) {
        const int wcol = whalf * 32 + nt * 16 + c0;
#pragma unroll
        for (int r = 0; r < 4; ++r) {
            const int o = o4 + r;
            out[(((size_t)b * NO + o) * NH + h) * NW + wcol] = outacc[nt][r];
        }
    }
}

extern "C" void kernel_launch(void* const* d_in, const int* in_sizes, int n_in,
                              void* d_out, int out_size, void* d_ws, size_t ws_size,
                              hipStream_t stream) {
    const float* x       = (const float*)d_in[0];
    const float* w_gen   = (const float*)d_in[1];
    const float* b_gen   = (const float*)d_in[2];
    const float* pos_enc = (const float*)d_in[3];
    float* out = (float*)d_out;

    dim3 grid(NB * NH);   // 512 workgroups -> 2 per CU
    dim3 block(512);
    hipLaunchKernelGGL(acda_kernel, grid, block, 0, stream,
                       x, w_gen, b_gen, pos_enc, out);
}